// Round 6
// baseline (1948.477 us; speedup 1.0000x reference)
//
#include <hip/hip_runtime.h>

// NeuroVoltron v10: v9 (flagless NaN-sentinel z-exchange, 3 rotating buffers)
// with the implicit-vmcnt(0) barrier drains removed. hipcc's __syncthreads
// emits "s_waitcnt vmcnt(0) expcnt(0) lgkmcnt(0); s_barrier" — draining nt
// output stores + agent publishes to HBM/MALL ack at EVERY phase boundary
// (~2-4us/step). With data-polling, no consumer needs those drains:
//  - LDS handoffs need only lgkmcnt(0): raw s_barrier + lgkm wait (HK style).
//  - Poison-before-publish ordering is intra-wave-7 (poison lanes 480-511,
//    publish lanes 464-495 are the same wave): wave 7 runs a private
//    s_waitcnt vmcnt(0) during P3 (it is idle there), hiding the drain under
//    other waves' P3 compute.
//  - out_z / out_msgs nt-stores are drained only by kernel-end.
// Everything else (protocol, lane maps, arithmetic) identical to v9:
//  - publish z_{t+1} into buf (t+1)%3 (relaxed agent stores); consumers poll
//    the DATA (chunk ready = all 4 words non-NaN); detection+data = one MALL
//    round trip overlapped with P4 compute.
//  - fetch team = tids 304-447 (waves 4-6 only; wave-7 spin/store deadlock
//    invariant from v9 preserved).
//  - own record re-poisoned in P2 for buf (t-1)%3.
// Arithmetic identical => absmax 0.015625.

constexpr int R  = 12;
constexpr int L  = 32;
constexpr int M  = 16;
constexpr int HH = 32;
constexpr int HF = 64;
constexpr int E  = 132;
constexpr int G3 = 96;      // 3*HH
constexpr float DT = 0.1f;

constexpr int G  = 4;       // batch elements per block
constexpr int BS = 512;

typedef float f4v __attribute__((ext_vector_type(4)));   // nt-store-compatible

__device__ __forceinline__ float sigmoidf(float x) {
    return 1.0f / (1.0f + __expf(-x));
}
__device__ __forceinline__ float fma4(float4 a, float4 x, float acc) {
    acc = fmaf(a.x, x.x, acc);
    acc = fmaf(a.y, x.y, acc);
    acc = fmaf(a.z, x.z, acc);
    return fmaf(a.w, x.w, acc);
}

// Raw block barrier: LDS-only ordering (lgkmcnt), NO vmcnt drain.
// Memory-clobber asm brackets stop the compiler moving LDS ops across.
__device__ __forceinline__ void sync_lds() {
    asm volatile("s_waitcnt lgkmcnt(0)" ::: "memory");
    __builtin_amdgcn_s_barrier();
    asm volatile("" ::: "memory");
}

__global__ __launch_bounds__(BS) void nv_main(
    const float* __restrict__ z0,     const float* __restrict__ h0,
    const float* __restrict__ mean_w, const float* __restrict__ mean_b,
    const float* __restrict__ add_w,
    const float* __restrict__ gsw,    const float* __restrict__ gsb,
    const float* __restrict__ gcw,
    const float* __restrict__ lw,     const float* __restrict__ lb,
    const float* __restrict__ ow_w,   const float* __restrict__ ob,
    const float* __restrict__ wih,    const float* __restrict__ whh,
    const float* __restrict__ bih,    const float* __restrict__ bhh,
    const int* __restrict__ src_idx,  const int* __restrict__ tgt_idx,
    const int* __restrict__ n_steps_p,
    float* __restrict__ zx,
    float* __restrict__ out, int B)
{
    const int r   = blockIdx.x;       // room
    const int grp = blockIdx.y;       // batch group
    const int tid = threadIdx.x;
    const int T   = n_steps_p[0];
    const int b0  = grp * G;
    const size_t ZXN = (size_t)B * (R * L);   // one buffer's floats

    // output layout: z_traj (B,T,R,L) | h_f (B,R,HH) | msgs (B,T,E,M)
    float* __restrict__ out_z    = out;
    float* __restrict__ out_hf   = out + (size_t)B * T * R * L;
    float* __restrict__ out_msgs = out_hf + (size_t)B * R * HH;

    __shared__ __align__(16) float wadd_s[11 * L * M];   // [(e*4+c)*32+l] packed f4 over m
    __shared__ __align__(16) float zS[G * R * L];        // [g][room][l]
    __shared__ __align__(16) float hSS[G * HH];          // [g][hh] (own room)
    __shared__ __align__(16) float meanS[G * 11 * M];    // [g][e_local*16+m]
    __shared__ __align__(16) float incS[G * L];
    __shared__ __align__(16) float gateS[G * L];
    __shared__ __align__(16) float shSS[G * HF];
    __shared__ __align__(16) float giSS[G * G3];
    __shared__ __align__(16) float ghSS[G * G3];
    __shared__ int edgeE[11], edgeSrc[11];

    // ---- edge tables for this room ----
    if (tid == 0) {
        int c = 0;
        for (int e = 0; e < E; ++e)
            if (tgt_idx[e] == r) { edgeE[c] = e; edgeSrc[c] = src_idx[e]; ++c; }
    }
    __syncthreads();

    // ---- one-time: load my weight row into registers (uniform wbuf union) ----
    float4 wbuf[16];
#pragma unroll
    for (int k = 0; k < 16; ++k) wbuf[k] = make_float4(0.f, 0.f, 0.f, 0.f);
    float bias = 0.f;
    const float4* wsA = nullptr;
    const float4* wsB = nullptr;
    if (tid < 176) {                       // mean rows: (e_local, m)
        const int el = tid >> 4, m = tid & 15;
        const int row = edgeE[el] * M + m;
        wsA = (const float4*)(mean_w + (size_t)row * L);
        bias = mean_b[row];
    } else if (tid < 272) {                // gh rows (whh)
        const int j = tid - 176, row = r * G3 + j;
        wsA = (const float4*)(whh + (size_t)row * HH);
        bias = bhh[row];
    } else if (tid < 304) {                // gate rows (gsw || gcw)
        const int j = tid - 272, row = r * L + j;
        wsA = (const float4*)(gsw + (size_t)row * L);
        wsB = (const float4*)(gcw + (size_t)row * L);
        bias = gsb[row];
    } else if (tid < 368) {                // silu rows (lw, 64 wide)
        const int j = tid - 304, row = r * HF + j;
        wsA = (const float4*)(lw + (size_t)row * 2 * L);
        wsB = wsA + 8;
        bias = lb[row];
    } else if (tid < 464) {                // gi rows (wih)
        const int j = tid - 368, row = r * G3 + j;
        wsA = (const float4*)(wih + (size_t)row * L);
        bias = bih[row];
    } else if (tid < 496) {                // ow rows (64 wide)
        const int j = tid - 464, row = r * L + j;
        wsA = (const float4*)(ow_w + (size_t)row * HF);
        wsB = wsA + 8;
        bias = ob[row];
    }
    if (wsA) {
#pragma unroll
        for (int k = 0; k < 8; ++k) wbuf[k] = wsA[k];
    }
    if (wsB) {
#pragma unroll
        for (int k = 0; k < 8; ++k) wbuf[8 + k] = wsB[k];
    }

    // ---- one-time: add_w slice -> LDS (transposed, f4-packed over m) ----
    for (int i = tid; i < 11 * L * M; i += BS) {
        const int e = i >> 9, rem = i & 511, l = rem >> 4, m = rem & 15;
        wadd_s[((e * 4 + (m >> 2)) * 32 + l) * 4 + (m & 3)] =
            add_w[((size_t)edgeE[e] * L + l) * M + m];
    }
    // ---- state init ----
    for (int i = tid; i < G * R * L; i += BS) {
        const int g = i / (R * L), rl = i - g * (R * L);
        zS[i] = z0[(size_t)(b0 + g) * R * L + rl];
    }
    for (int i = tid; i < G * HH; i += BS) {
        const int g = i >> 5, hh = i & 31;
        hSS[i] = h0[(size_t)(b0 + g) * R * HH + r * HH + hh];
    }
    __syncthreads();

    const float NANF = __uint_as_float(0xFFFFFFFFu);

    for (int t = 0; t < T; ++t) {
        // ---- P1: mean (0-175) | gh (176-271) ----
        if (tid < 176) {
            const int el = tid >> 4, m = tid & 15;
            const int sr = edgeSrc[el];
#pragma unroll
            for (int g = 0; g < G; ++g) {
                const float4* zp = (const float4*)(zS + g * (R * L) + sr * L);
                float a = bias;
#pragma unroll
                for (int c = 0; c < 8; ++c) a = fma4(wbuf[c], zp[c], a);
                meanS[g * 176 + el * 16 + m] = a;
            }
        } else if (tid < 272) {
            const int j = tid - 176;
#pragma unroll
            for (int g = 0; g < G; ++g) {
                const float4* hp = (const float4*)(hSS + g * HH);
                float a = bias;
#pragma unroll
                for (int c = 0; c < 8; ++c) a = fma4(wbuf[c], hp[c], a);
                ghSS[g * G3 + j] = a;
            }
        }
        sync_lds();

        // ---- P2: inc (0-127) | re-poison own record of buf (t-1)%3 (480-511) ----
        if (tid < 128) {
            const int g = tid >> 5, l = tid & 31;
            const float4* mp = (const float4*)(meanS + g * 176);
            const float4* wp = (const float4*)wadd_s;
            float a = 0.f;
#pragma unroll
            for (int e = 0; e < 11; ++e)
#pragma unroll
                for (int c = 0; c < 4; ++c)
                    a = fma4(wp[(e * 4 + c) * 32 + l], mp[e * 4 + c], a);
            incS[g * L + l] = a;
        } else if (tid >= 480 && t >= 1) {
            // Poison own room's record in the buffer last read 2 steps ago.
            // Ordering vs this step's publish is enforced INSIDE wave 7:
            // an explicit vmcnt(0) during P3 (below) drains these before the
            // publish lanes (same wave) issue their P4 stores.
            float* __restrict__ zq = zx + (size_t)((t - 1) % 3) * ZXN;
            const int i = tid - 480;              // 0..31
            const int g = i >> 3, l4 = i & 7;
            float* pp = zq + (size_t)(b0 + g) * (R * L) + r * L + l4 * 4;
#pragma unroll
            for (int w = 0; w < 4; ++w)
                __hip_atomic_store(pp + w, NANF, __ATOMIC_RELAXED,
                                   __HIP_MEMORY_SCOPE_AGENT);
        }
        sync_lds();

        // ---- P3: gate (272-303) | silu (304-367) | gi (368-463)
        //         | wave 7 (448-511): private poison drain, hidden here ----
        if (tid >= 272 && tid < 304) {
            const int j = tid - 272;
#pragma unroll
            for (int g = 0; g < G; ++g) {
                const float4* zp = (const float4*)(zS + g * (R * L) + r * L);
                const float4* ip = (const float4*)(incS + g * L);
                float a = bias;
#pragma unroll
                for (int c = 0; c < 8; ++c) {
                    a = fma4(wbuf[c], zp[c], a);
                    a = fma4(wbuf[8 + c], ip[c], a);
                }
                gateS[g * L + j] = sigmoidf(a);
            }
        } else if (tid >= 304 && tid < 368) {
            const int j = tid - 304;
#pragma unroll
            for (int g = 0; g < G; ++g) {
                const float4* zp = (const float4*)(zS + g * (R * L) + r * L);
                const float4* ip = (const float4*)(incS + g * L);
                float a = bias;
#pragma unroll
                for (int c = 0; c < 8; ++c) {
                    a = fma4(wbuf[c], zp[c], a);
                    a = fma4(wbuf[8 + c], ip[c], a);
                }
                shSS[g * HF + j] = a * sigmoidf(a);
            }
        } else if (tid >= 368 && tid < 464) {
            const int j = tid - 368;
#pragma unroll
            for (int g = 0; g < G; ++g) {
                const float4* ip = (const float4*)(incS + g * L);
                float a = bias;
#pragma unroll
                for (int c = 0; c < 8; ++c) a = fma4(wbuf[c], ip[c], a);
                giSS[g * G3 + j] = a;
            }
        } else if (tid >= 448) {
            // Wave 7 only (s_waitcnt is wave-scalar): drain the poison stores
            // while waves 4-6 compute P3. Publish (same wave) issues after.
            asm volatile("s_waitcnt vmcnt(0)" ::: "memory");
        }
        sync_lds();

        // ---- P4: zout+publish (464-495, wave 7) | GRU (176-303) | msgs (0-175)
        //         | FETCH remote z for t+1 (304-447, waves 4-6 ONLY) ----
        float* __restrict__ zxp = zx + (size_t)((t + 1) % 3) * ZXN;
        if (tid >= 464 && tid < 496) {
            const int j = tid - 464;
#pragma unroll
            for (int g = 0; g < G; ++g) {
                const float4* sp = (const float4*)(shSS + g * HF);
                float a = bias;
#pragma unroll
                for (int c = 0; c < 16; ++c) a = fma4(wbuf[c], sp[c], a);
                const float target = tanhf(a);
                const float zv = zS[g * (R * L) + r * L + j];
                const float znew = zv + DT * gateS[g * L + j] * (target - zv);
                zS[g * (R * L) + r * L + j] = znew;   // own-room z stays in LDS
                if (t + 1 < T)
                    __hip_atomic_store(&zxp[(size_t)(b0 + g) * (R * L) + r * L + j],
                                       znew, __ATOMIC_RELAXED,
                                       __HIP_MEMORY_SCOPE_AGENT);
                __builtin_nontemporal_store(
                    znew, &out_z[((size_t)(b0 + g) * T + t) * (R * L) + r * L + j]);
            }
        } else if (tid >= 176 && tid < 304) {
            const int i = tid - 176;
            const int g = i >> 5, hh = i & 31;
            const float ir  = giSS[g * G3 + hh];
            const float iz  = giSS[g * G3 + HH + hh];
            const float inn = giSS[g * G3 + 2 * HH + hh];
            const float hr  = ghSS[g * G3 + hh];
            const float hz  = ghSS[g * G3 + HH + hh];
            const float hnv = ghSS[g * G3 + 2 * HH + hh];
            const float reset = sigmoidf(ir + hr);
            const float upd   = sigmoidf(iz + hz);
            const float nw    = tanhf(inn + reset * hnv);
            hSS[g * HH + hh] = (1.0f - upd) * nw + upd * hSS[g * HH + hh];
        } else if (tid < 176) {
            const int g = tid / 44, i = tid - g * 44;     // i in 0..43 (f4 over 11*M)
            const int el = i >> 2, m4 = i & 3;
            const f4v v = *(const f4v*)(meanS + g * 176 + i * 4);
            __builtin_nontemporal_store(
                v, (f4v*)&out_msgs[((size_t)(b0 + g) * T + t) * (E * M)
                                   + edgeE[el] * 16 + m4 * 4]);
        } else if (tid >= 304 && tid < 448) {
            // FETCH team: 144 threads (waves 4-6), 352 chunks of 16B
            // (11 rooms x G x 8). NO wave-7 lanes (deadlock invariant).
            if (t + 1 < T) {
                const int ft = tid - 304;        // 0..143
                for (int c = ft; c < 352; c += 144) {
                    const int team = c >> 5, rem = c & 31;
                    const int s    = team + (team >= r ? 1 : 0);   // remote room
                    const int g    = rem >> 3, l4 = rem & 7;
                    const float* sp =
                        zxp + (size_t)(b0 + g) * (R * L) + s * L + l4 * 4;
                    float4 v;
                    for (;;) {
                        v.x = __hip_atomic_load(sp + 0, __ATOMIC_RELAXED, __HIP_MEMORY_SCOPE_AGENT);
                        v.y = __hip_atomic_load(sp + 1, __ATOMIC_RELAXED, __HIP_MEMORY_SCOPE_AGENT);
                        v.z = __hip_atomic_load(sp + 2, __ATOMIC_RELAXED, __HIP_MEMORY_SCOPE_AGENT);
                        v.w = __hip_atomic_load(sp + 3, __ATOMIC_RELAXED, __HIP_MEMORY_SCOPE_AGENT);
                        // ready iff all 4 words are non-NaN (values never NaN)
                        if (v.x == v.x && v.y == v.y && v.z == v.z && v.w == v.w)
                            break;
                        __builtin_amdgcn_s_sleep(1);
                    }
                    ((float4*)zS)[g * (R * L / 4) + s * (L / 4) + l4] = v;
                }
            }
        }
        sync_lds();
    }

    // ---- final h ----
    for (int i = tid; i < G * HH; i += BS) {
        const int g = i >> 5, hh = i & 31;
        __builtin_nontemporal_store(
            hSS[i], &out_hf[(size_t)(b0 + g) * R * HH + r * HH + hh]);
    }
}

extern "C" void kernel_launch(void* const* d_in, const int* in_sizes, int n_in,
                              void* d_out, int out_size, void* d_ws, size_t ws_size,
                              hipStream_t stream) {
    const float* z0     = (const float*)d_in[0];
    const float* h0     = (const float*)d_in[1];
    const float* mean_w = (const float*)d_in[2];
    const float* mean_b = (const float*)d_in[3];
    const float* add_w  = (const float*)d_in[4];
    const float* gsw    = (const float*)d_in[5];
    const float* gsb    = (const float*)d_in[6];
    const float* gcw    = (const float*)d_in[7];
    const float* lw     = (const float*)d_in[8];
    const float* lb     = (const float*)d_in[9];
    const float* ow_w   = (const float*)d_in[10];
    const float* ob     = (const float*)d_in[11];
    const float* wih    = (const float*)d_in[12];
    const float* whh    = (const float*)d_in[13];
    const float* bih    = (const float*)d_in[14];
    const float* bhh    = (const float*)d_in[15];
    const int* src_idx  = (const int*)d_in[16];
    const int* tgt_idx  = (const int*)d_in[17];
    const int* n_steps  = (const int*)d_in[18];

    const int B  = in_sizes[0] / (R * L);
    const int NG = B / G;   // batch groups

    float* zx = (float*)d_ws;    // 3 rotating buffers of B*R*L floats

    // Pre-poison all three buffers: every word = 0xFFFFFFFF = NaN sentinel.
    (void)hipMemsetAsync(zx, 0xFF, (size_t)3 * B * R * L * sizeof(float), stream);

    nv_main<<<dim3(R, NG), dim3(BS), 0, stream>>>(
        z0, h0, mean_w, mean_b, add_w, gsw, gsb, gcw, lw, lb, ow_w, ob,
        wih, whh, bih, bhh, src_idx, tgt_idx, n_steps,
        zx, (float*)d_out, B);
}

// Round 7
// 1881.016 us; speedup vs baseline: 1.0359x; 1.0359x over previous
//
#include <hip/hip_runtime.h>

// NeuroVoltron v11: wave-aligned roles + wadd in registers. Exchange protocol
// identical to v10 (flagless NaN-sentinel data-polling, 3 rotating buffers,
// lgkm-only barriers) — four protocol variants all measured ~9.1us/step, and
// poll-retry counters show remote data is already visible when asked; the cost
// is intra-block. Changes:
//  - Every role now occupies whole waves (no intra-wave role mixing, which
//    serialized divergent branches): mean W0-2, gh W3-4, inc W0-1, gate W3,
//    silu W4, gi W5-6, GRU W5-6, zout+poison W7, msgs W0-2, fetch W3-4.
//    Deadlock invariant kept: fetch waves (3,4) contain no publish stores (W7).
//  - wadd (22KB) moved from LDS to registers of the inc threads (44 f4/thread
//    in a uniform wbuf[52] union, ~230 VGPR total at 2 waves/SIMD) — halves
//    P2's LDS instruction count and shrinks LDS to ~15KB.
// All dot-product summation orders unchanged => absmax identical (0.015625).

constexpr int R  = 12;
constexpr int L  = 32;
constexpr int M  = 16;
constexpr int HH = 32;
constexpr int HF = 64;
constexpr int E  = 132;
constexpr int G3 = 96;      // 3*HH
constexpr float DT = 0.1f;

constexpr int G  = 4;       // batch elements per block
constexpr int BS = 512;

typedef float f4v __attribute__((ext_vector_type(4)));   // nt-store-compatible

__device__ __forceinline__ float sigmoidf(float x) {
    return 1.0f / (1.0f + __expf(-x));
}
__device__ __forceinline__ float fma4(float4 a, float4 x, float acc) {
    acc = fmaf(a.x, x.x, acc);
    acc = fmaf(a.y, x.y, acc);
    acc = fmaf(a.z, x.z, acc);
    return fmaf(a.w, x.w, acc);
}

// Raw block barrier: LDS-only ordering (lgkmcnt), no vmcnt drain.
__device__ __forceinline__ void sync_lds() {
    asm volatile("s_waitcnt lgkmcnt(0)" ::: "memory");
    __builtin_amdgcn_s_barrier();
    asm volatile("" ::: "memory");
}

__global__ __launch_bounds__(BS, 2) void nv_main(
    const float* __restrict__ z0,     const float* __restrict__ h0,
    const float* __restrict__ mean_w, const float* __restrict__ mean_b,
    const float* __restrict__ add_w,
    const float* __restrict__ gsw,    const float* __restrict__ gsb,
    const float* __restrict__ gcw,
    const float* __restrict__ lw,     const float* __restrict__ lb,
    const float* __restrict__ ow_w,   const float* __restrict__ ob,
    const float* __restrict__ wih,    const float* __restrict__ whh,
    const float* __restrict__ bih,    const float* __restrict__ bhh,
    const int* __restrict__ src_idx,  const int* __restrict__ tgt_idx,
    const int* __restrict__ n_steps_p,
    float* __restrict__ zx,
    float* __restrict__ out, int B)
{
    const int r   = blockIdx.x;       // room
    const int grp = blockIdx.y;       // batch group
    const int tid = threadIdx.x;
    const int T   = n_steps_p[0];
    const int b0  = grp * G;
    const size_t ZXN = (size_t)B * (R * L);   // one buffer's floats

    // output layout: z_traj (B,T,R,L) | h_f (B,R,HH) | msgs (B,T,E,M)
    float* __restrict__ out_z    = out;
    float* __restrict__ out_hf   = out + (size_t)B * T * R * L;
    float* __restrict__ out_msgs = out_hf + (size_t)B * R * HH;

    __shared__ __align__(16) float zS[G * R * L];        // [g][room][l]
    __shared__ __align__(16) float hSS[G * HH];          // [g][hh] (own room)
    __shared__ __align__(16) float meanS[G * 11 * M];    // [g][e_local*16+m]
    __shared__ __align__(16) float incS[G * L];
    __shared__ __align__(16) float gateS[G * L];
    __shared__ __align__(16) float shSS[G * HF];
    __shared__ __align__(16) float giSS[G * G3];
    __shared__ __align__(16) float ghSS[G * G3];
    __shared__ int edgeE[11], edgeSrc[11];

    // ---- edge tables for this room ----
    if (tid == 0) {
        int c = 0;
        for (int e = 0; e < E; ++e)
            if (tgt_idx[e] == r) { edgeE[c] = e; edgeSrc[c] = src_idx[e]; ++c; }
    }
    __syncthreads();

    // ---- one-time: weights into the uniform wbuf[52] register union ----
    // slots: [0..7]  mean row (W0-2) | gh row (W3-4) | gi row (W5-6)
    //        [8..51] wadd 44xf4 (W0-1 only)
    //        [8..23] gate gsw+gcw (W3) | silu lw (W4) | ow row (W7 lower)
    float4 wbuf[52];
    float biasA = 0.f, biasB = 0.f;

    if (tid < 176) {                       // mean rows: (el, m)
        const int el = tid >> 4, m = tid & 15;
        const int row = edgeE[el] * M + m;
        const float4* p = (const float4*)(mean_w + (size_t)row * L);
#pragma unroll
        for (int k = 0; k < 8; ++k) wbuf[k] = p[k];
        biasA = mean_b[row];
    }
    if (tid < 128) {                       // wadd regs: depend only on l
        const int l = tid & 31;
#pragma unroll
        for (int e = 0; e < 11; ++e) {
            const int eg = edgeE[e];
#pragma unroll
            for (int c = 0; c < 4; ++c)
                wbuf[8 + e * 4 + c] =
                    *(const float4*)(add_w + ((size_t)eg * L + l) * M + c * 4);
        }
    }
    if (tid >= 192 && tid < 288) {         // gh rows (whh), j=tid-192
        const int j = tid - 192, row = r * G3 + j;
        const float4* p = (const float4*)(whh + (size_t)row * HH);
#pragma unroll
        for (int k = 0; k < 8; ++k) wbuf[k] = p[k];
        biasA = bhh[row];
    }
    if (tid >= 192 && tid < 224) {         // gate rows: gsw -> [8..15], gcw -> [16..23]
        const int j = tid - 192, row = r * L + j;
        const float4* pa = (const float4*)(gsw + (size_t)row * L);
        const float4* pb = (const float4*)(gcw + (size_t)row * L);
#pragma unroll
        for (int k = 0; k < 8; ++k) { wbuf[8 + k] = pa[k]; wbuf[16 + k] = pb[k]; }
        biasB = gsb[row];
    }
    if (tid >= 256 && tid < 320) {         // silu rows (lw, 64 wide) -> [8..23]
        const int j = tid - 256, row = r * HF + j;
        const float4* p = (const float4*)(lw + (size_t)row * 2 * L);
#pragma unroll
        for (int k = 0; k < 16; ++k) wbuf[8 + k] = p[k];
        biasB = lb[row];
    }
    if (tid >= 320 && tid < 416) {         // gi rows (wih), j=tid-320
        const int j = tid - 320, row = r * G3 + j;
        const float4* p = (const float4*)(wih + (size_t)row * L);
#pragma unroll
        for (int k = 0; k < 8; ++k) wbuf[k] = p[k];
        biasA = bih[row];
    }
    if (tid >= 448 && tid < 480) {         // ow rows (64 wide) -> [8..23]
        const int j = tid - 448, row = r * L + j;
        const float4* p = (const float4*)(ow_w + (size_t)row * HF);
#pragma unroll
        for (int k = 0; k < 16; ++k) wbuf[8 + k] = p[k];
        biasB = ob[row];
    }

    // ---- state init ----
    for (int i = tid; i < G * R * L; i += BS) {
        const int g = i / (R * L), rl = i - g * (R * L);
        zS[i] = z0[(size_t)(b0 + g) * R * L + rl];
    }
    for (int i = tid; i < G * HH; i += BS) {
        const int g = i >> 5, hh = i & 31;
        hSS[i] = h0[(size_t)(b0 + g) * R * HH + r * HH + hh];
    }
    __syncthreads();

    const float NANF = __uint_as_float(0xFFFFFFFFu);

    for (int t = 0; t < T; ++t) {
        // ---- P1: mean (W0-2: 0-175) | gh (W3-4: 192-287) ----
        if (tid < 176) {
            const int el = tid >> 4, m = tid & 15;
            const int sr = edgeSrc[el];
            (void)m;
#pragma unroll
            for (int g = 0; g < G; ++g) {
                const float4* zp = (const float4*)(zS + g * (R * L) + sr * L);
                float a = biasA;
#pragma unroll
                for (int c = 0; c < 8; ++c) a = fma4(wbuf[c], zp[c], a);
                meanS[g * 176 + (tid & 15) + (el << 4)] = a;
            }
        } else if (tid >= 192 && tid < 288) {
            const int j = tid - 192;
#pragma unroll
            for (int g = 0; g < G; ++g) {
                const float4* hp = (const float4*)(hSS + g * HH);
                float a = biasA;
#pragma unroll
                for (int c = 0; c < 8; ++c) a = fma4(wbuf[c], hp[c], a);
                ghSS[g * G3 + j] = a;
            }
        }
        sync_lds();

        // ---- P2: inc (W0-1: 0-127, wadd in regs) | poison (W7 upper) ----
        if (tid < 128) {
            const int g = tid >> 5, l = tid & 31;
            (void)l;
            const float4* mp = (const float4*)(meanS + g * 176);
            float a = 0.f;
#pragma unroll
            for (int e = 0; e < 11; ++e)
#pragma unroll
                for (int c = 0; c < 4; ++c)
                    a = fma4(wbuf[8 + e * 4 + c], mp[e * 4 + c], a);
            incS[tid] = a;      // tid = g*32+l
        } else if (tid >= 480 && t >= 1) {
            // Poison own room's record in the buffer last read 2 steps ago.
            // Ordering vs this step's publish is intra-wave-7 (drain in P3).
            float* __restrict__ zq = zx + (size_t)((t - 1) % 3) * ZXN;
            const int i = tid - 480;              // 0..31
            const int g = i >> 3, l4 = i & 7;
            float* pp = zq + (size_t)(b0 + g) * (R * L) + r * L + l4 * 4;
#pragma unroll
            for (int w = 0; w < 4; ++w)
                __hip_atomic_store(pp + w, NANF, __ATOMIC_RELAXED,
                                   __HIP_MEMORY_SCOPE_AGENT);
        }
        sync_lds();

        // ---- P3: gate (W3: 192-223) | silu (W4: 256-319) | gi (W5-6: 320-415)
        //         | W7: private poison drain ----
        if (tid >= 192 && tid < 224) {
            const int j = tid - 192;
#pragma unroll
            for (int g = 0; g < G; ++g) {
                const float4* zp = (const float4*)(zS + g * (R * L) + r * L);
                const float4* ip = (const float4*)(incS + g * L);
                float a = biasB;
#pragma unroll
                for (int c = 0; c < 8; ++c) {
                    a = fma4(wbuf[8 + c], zp[c], a);
                    a = fma4(wbuf[16 + c], ip[c], a);
                }
                gateS[g * L + j] = sigmoidf(a);
            }
        } else if (tid >= 256 && tid < 320) {
            const int j = tid - 256;
#pragma unroll
            for (int g = 0; g < G; ++g) {
                const float4* zp = (const float4*)(zS + g * (R * L) + r * L);
                const float4* ip = (const float4*)(incS + g * L);
                float a = biasB;
#pragma unroll
                for (int c = 0; c < 8; ++c) {
                    a = fma4(wbuf[8 + c], zp[c], a);
                    a = fma4(wbuf[16 + c], ip[c], a);
                }
                shSS[g * HF + j] = a * sigmoidf(a);
            }
        } else if (tid >= 320 && tid < 416) {
            const int j = tid - 320;
#pragma unroll
            for (int g = 0; g < G; ++g) {
                const float4* ip = (const float4*)(incS + g * L);
                float a = biasA;
#pragma unroll
                for (int c = 0; c < 8; ++c) a = fma4(wbuf[c], ip[c], a);
                giSS[g * G3 + j] = a;
            }
        } else if (tid >= 448) {
            // Wave 7 (s_waitcnt is wave-scalar): drain poison stores while
            // other waves compute P3; publish (same wave) issues after.
            asm volatile("s_waitcnt vmcnt(0)" ::: "memory");
        }
        sync_lds();

        // ---- P4: zout+publish (W7 lower: 448-479) | GRU (W5-6: 320-447)
        //         | msgs (W0-2: 0-175) | fetch (W3-4: 192-319) ----
        float* __restrict__ zxp = zx + (size_t)((t + 1) % 3) * ZXN;
        if (tid >= 448 && tid < 480) {
            const int j = tid - 448;
#pragma unroll
            for (int g = 0; g < G; ++g) {
                const float4* sp = (const float4*)(shSS + g * HF);
                float a = biasB;
#pragma unroll
                for (int c = 0; c < 16; ++c) a = fma4(wbuf[8 + c], sp[c], a);
                const float target = tanhf(a);
                const float zv = zS[g * (R * L) + r * L + j];
                const float znew = zv + DT * gateS[g * L + j] * (target - zv);
                zS[g * (R * L) + r * L + j] = znew;   // own-room z stays in LDS
                if (t + 1 < T)
                    __hip_atomic_store(&zxp[(size_t)(b0 + g) * (R * L) + r * L + j],
                                       znew, __ATOMIC_RELAXED,
                                       __HIP_MEMORY_SCOPE_AGENT);
                __builtin_nontemporal_store(
                    znew, &out_z[((size_t)(b0 + g) * T + t) * (R * L) + r * L + j]);
            }
        } else if (tid >= 320 && tid < 448) {
            const int i = tid - 320;
            const int g = i >> 5, hh = i & 31;
            const float ir  = giSS[g * G3 + hh];
            const float iz  = giSS[g * G3 + HH + hh];
            const float inn = giSS[g * G3 + 2 * HH + hh];
            const float hr  = ghSS[g * G3 + hh];
            const float hz  = ghSS[g * G3 + HH + hh];
            const float hnv = ghSS[g * G3 + 2 * HH + hh];
            const float reset = sigmoidf(ir + hr);
            const float upd   = sigmoidf(iz + hz);
            const float nw    = tanhf(inn + reset * hnv);
            hSS[g * HH + hh] = (1.0f - upd) * nw + upd * hSS[g * HH + hh];
        } else if (tid < 176) {
            const int g = tid / 44, i = tid - g * 44;     // i in 0..43 (f4 over 11*M)
            const int el = i >> 2, m4 = i & 3;
            const f4v v = *(const f4v*)(meanS + g * 176 + i * 4);
            __builtin_nontemporal_store(
                v, (f4v*)&out_msgs[((size_t)(b0 + g) * T + t) * (E * M)
                                   + edgeE[el] * 16 + m4 * 4]);
        } else if (tid >= 192 && tid < 320) {
            // FETCH team: W3-4 (128 lanes), 352 chunks of 16B (11 rooms x G x 8).
            // No wave-7 lanes (deadlock invariant: publishers are W7).
            if (t + 1 < T) {
                const int k = tid - 192;         // 0..127
                for (int c = k; c < 352; c += 128) {
                    const int team = c >> 5, rem = c & 31;
                    const int s    = team + (team >= r ? 1 : 0);   // remote room
                    const int g    = rem >> 3, l4 = rem & 7;
                    const float* sp =
                        zxp + (size_t)(b0 + g) * (R * L) + s * L + l4 * 4;
                    float4 v;
                    for (;;) {
                        v.x = __hip_atomic_load(sp + 0, __ATOMIC_RELAXED, __HIP_MEMORY_SCOPE_AGENT);
                        v.y = __hip_atomic_load(sp + 1, __ATOMIC_RELAXED, __HIP_MEMORY_SCOPE_AGENT);
                        v.z = __hip_atomic_load(sp + 2, __ATOMIC_RELAXED, __HIP_MEMORY_SCOPE_AGENT);
                        v.w = __hip_atomic_load(sp + 3, __ATOMIC_RELAXED, __HIP_MEMORY_SCOPE_AGENT);
                        if (v.x == v.x && v.y == v.y && v.z == v.z && v.w == v.w)
                            break;
                        __builtin_amdgcn_s_sleep(1);
                    }
                    ((float4*)zS)[g * (R * L / 4) + s * (L / 4) + l4] = v;
                }
            }
        }
        sync_lds();
    }

    // ---- final h ----
    for (int i = tid; i < G * HH; i += BS) {
        const int g = i >> 5, hh = i & 31;
        __builtin_nontemporal_store(
            hSS[i], &out_hf[(size_t)(b0 + g) * R * HH + r * HH + hh]);
    }
}

extern "C" void kernel_launch(void* const* d_in, const int* in_sizes, int n_in,
                              void* d_out, int out_size, void* d_ws, size_t ws_size,
                              hipStream_t stream) {
    const float* z0     = (const float*)d_in[0];
    const float* h0     = (const float*)d_in[1];
    const float* mean_w = (const float*)d_in[2];
    const float* mean_b = (const float*)d_in[3];
    const float* add_w  = (const float*)d_in[4];
    const float* gsw    = (const float*)d_in[5];
    const float* gsb    = (const float*)d_in[6];
    const float* gcw    = (const float*)d_in[7];
    const float* lw     = (const float*)d_in[8];
    const float* lb     = (const float*)d_in[9];
    const float* ow_w   = (const float*)d_in[10];
    const float* ob     = (const float*)d_in[11];
    const float* wih    = (const float*)d_in[12];
    const float* whh    = (const float*)d_in[13];
    const float* bih    = (const float*)d_in[14];
    const float* bhh    = (const float*)d_in[15];
    const int* src_idx  = (const int*)d_in[16];
    const int* tgt_idx  = (const int*)d_in[17];
    const int* n_steps  = (const int*)d_in[18];

    const int B  = in_sizes[0] / (R * L);
    const int NG = B / G;   // batch groups

    float* zx = (float*)d_ws;    // 3 rotating buffers of B*R*L floats

    // Pre-poison all three buffers: every word = 0xFFFFFFFF = NaN sentinel.
    (void)hipMemsetAsync(zx, 0xFF, (size_t)3 * B * R * L * sizeof(float), stream);

    nv_main<<<dim3(R, NG), dim3(BS), 0, stream>>>(
        z0, h0, mean_w, mean_b, add_w, gsw, gsb, gcw, lw, lb, ow_w, ob,
        wih, whh, bih, bhh, src_idx, tgt_idx, n_steps,
        zx, (float*)d_out, B);
}

// Round 8
// 1673.709 us; speedup vs baseline: 1.1642x; 1.1239x over previous
//
#include <hip/hip_runtime.h>

// NeuroVoltron v12: v11 + three fixes aimed at the measured pathologies.
//  (1) amdgpu_waves_per_eu(2,2): v11's VGPR_Count=128 proved wbuf[52] (208
//      floats of weights) was silently spilled to scratch; allow 256 VGPRs.
//  (2) 72KB dynamic LDS at launch forces 1 block/CU (86.8KB > 160/2), killing
//      persistent stragglers from CU double-occupancy — candidate cause of the
//      protocol-invariant ~8.8us step.
//  (3) P4 fetch spread over W0-2(after msgs)+W3-4+W5-6(after GRU): 352 chunks,
//      <=1 per lane => one serial MALL round trip (was 3).
// Exchange protocol identical to v9/v10/v11 (flagless NaN-sentinel data-poll,
// 3 rotating buffers, lgkm-only barriers, W7-publishes-never-spins invariant).
// Arithmetic unchanged => absmax 0.015625.

constexpr int R  = 12;
constexpr int L  = 32;
constexpr int M  = 16;
constexpr int HH = 32;
constexpr int HF = 64;
constexpr int E  = 132;
constexpr int G3 = 96;      // 3*HH
constexpr float DT = 0.1f;

constexpr int G  = 4;       // batch elements per block
constexpr int BS = 512;

typedef float f4v __attribute__((ext_vector_type(4)));   // nt-store-compatible

__device__ __forceinline__ float sigmoidf(float x) {
    return 1.0f / (1.0f + __expf(-x));
}
__device__ __forceinline__ float fma4(float4 a, float4 x, float acc) {
    acc = fmaf(a.x, x.x, acc);
    acc = fmaf(a.y, x.y, acc);
    acc = fmaf(a.z, x.z, acc);
    return fmaf(a.w, x.w, acc);
}

// Raw block barrier: LDS-only ordering (lgkmcnt), no vmcnt drain.
__device__ __forceinline__ void sync_lds() {
    asm volatile("s_waitcnt lgkmcnt(0)" ::: "memory");
    __builtin_amdgcn_s_barrier();
    asm volatile("" ::: "memory");
}

__global__ __launch_bounds__(BS)
__attribute__((amdgpu_waves_per_eu(2, 2)))
void nv_main(
    const float* __restrict__ z0,     const float* __restrict__ h0,
    const float* __restrict__ mean_w, const float* __restrict__ mean_b,
    const float* __restrict__ add_w,
    const float* __restrict__ gsw,    const float* __restrict__ gsb,
    const float* __restrict__ gcw,
    const float* __restrict__ lw,     const float* __restrict__ lb,
    const float* __restrict__ ow_w,   const float* __restrict__ ob,
    const float* __restrict__ wih,    const float* __restrict__ whh,
    const float* __restrict__ bih,    const float* __restrict__ bhh,
    const int* __restrict__ src_idx,  const int* __restrict__ tgt_idx,
    const int* __restrict__ n_steps_p,
    float* __restrict__ zx,
    float* __restrict__ out, int B)
{
    const int r   = blockIdx.x;       // room
    const int grp = blockIdx.y;       // batch group
    const int tid = threadIdx.x;
    const int T   = n_steps_p[0];
    const int b0  = grp * G;
    const size_t ZXN = (size_t)B * (R * L);   // one buffer's floats

    // output layout: z_traj (B,T,R,L) | h_f (B,R,HH) | msgs (B,T,E,M)
    float* __restrict__ out_z    = out;
    float* __restrict__ out_hf   = out + (size_t)B * T * R * L;
    float* __restrict__ out_msgs = out_hf + (size_t)B * R * HH;

    __shared__ __align__(16) float zS[G * R * L];        // [g][room][l]
    __shared__ __align__(16) float hSS[G * HH];          // [g][hh] (own room)
    __shared__ __align__(16) float meanS[G * 11 * M];    // [g][e_local*16+m]
    __shared__ __align__(16) float incS[G * L];
    __shared__ __align__(16) float gateS[G * L];
    __shared__ __align__(16) float shSS[G * HF];
    __shared__ __align__(16) float giSS[G * G3];
    __shared__ __align__(16) float ghSS[G * G3];
    __shared__ int edgeE[11], edgeSrc[11];

    // ---- edge tables for this room ----
    if (tid == 0) {
        int c = 0;
        for (int e = 0; e < E; ++e)
            if (tgt_idx[e] == r) { edgeE[c] = e; edgeSrc[c] = src_idx[e]; ++c; }
    }
    __syncthreads();

    // ---- one-time: weights into the uniform wbuf[52] register union ----
    // slots: [0..7]  mean row (W0-2) | gh row (W3-4) | gi row (W5-6)
    //        [8..51] wadd 44xf4 (W0-1 only)
    //        [8..23] gate gsw+gcw (W3) | silu lw (W4) | ow row (W7 lower)
    float4 wbuf[52];
    float biasA = 0.f, biasB = 0.f;

    if (tid < 176) {                       // mean rows: (el, m)
        const int el = tid >> 4, m = tid & 15;
        const int row = edgeE[el] * M + m;
        const float4* p = (const float4*)(mean_w + (size_t)row * L);
#pragma unroll
        for (int k = 0; k < 8; ++k) wbuf[k] = p[k];
        biasA = mean_b[row];
    }
    if (tid < 128) {                       // wadd regs: depend only on l
        const int l = tid & 31;
#pragma unroll
        for (int e = 0; e < 11; ++e) {
            const int eg = edgeE[e];
#pragma unroll
            for (int c = 0; c < 4; ++c)
                wbuf[8 + e * 4 + c] =
                    *(const float4*)(add_w + ((size_t)eg * L + l) * M + c * 4);
        }
    }
    if (tid >= 192 && tid < 288) {         // gh rows (whh), j=tid-192
        const int j = tid - 192, row = r * G3 + j;
        const float4* p = (const float4*)(whh + (size_t)row * HH);
#pragma unroll
        for (int k = 0; k < 8; ++k) wbuf[k] = p[k];
        biasA = bhh[row];
    }
    if (tid >= 192 && tid < 224) {         // gate rows: gsw -> [8..15], gcw -> [16..23]
        const int j = tid - 192, row = r * L + j;
        const float4* pa = (const float4*)(gsw + (size_t)row * L);
        const float4* pb = (const float4*)(gcw + (size_t)row * L);
#pragma unroll
        for (int k = 0; k < 8; ++k) { wbuf[8 + k] = pa[k]; wbuf[16 + k] = pb[k]; }
        biasB = gsb[row];
    }
    if (tid >= 256 && tid < 320) {         // silu rows (lw, 64 wide) -> [8..23]
        const int j = tid - 256, row = r * HF + j;
        const float4* p = (const float4*)(lw + (size_t)row * 2 * L);
#pragma unroll
        for (int k = 0; k < 16; ++k) wbuf[8 + k] = p[k];
        biasB = lb[row];
    }
    if (tid >= 320 && tid < 416) {         // gi rows (wih), j=tid-320
        const int j = tid - 320, row = r * G3 + j;
        const float4* p = (const float4*)(wih + (size_t)row * L);
#pragma unroll
        for (int k = 0; k < 8; ++k) wbuf[k] = p[k];
        biasA = bih[row];
    }
    if (tid >= 448 && tid < 480) {         // ow rows (64 wide) -> [8..23]
        const int j = tid - 448, row = r * L + j;
        const float4* p = (const float4*)(ow_w + (size_t)row * HF);
#pragma unroll
        for (int k = 0; k < 16; ++k) wbuf[8 + k] = p[k];
        biasB = ob[row];
    }

    // ---- state init ----
    for (int i = tid; i < G * R * L; i += BS) {
        const int g = i / (R * L), rl = i - g * (R * L);
        zS[i] = z0[(size_t)(b0 + g) * R * L + rl];
    }
    for (int i = tid; i < G * HH; i += BS) {
        const int g = i >> 5, hh = i & 31;
        hSS[i] = h0[(size_t)(b0 + g) * R * HH + r * HH + hh];
    }
    __syncthreads();

    const float NANF = __uint_as_float(0xFFFFFFFFu);

    // one-chunk poll+load (chunk c in 0..351)
    auto fetch_chunk = [&](int c, const float* __restrict__ zxp) {
        const int team = c >> 5, rem = c & 31;
        const int s    = team + (team >= r ? 1 : 0);   // remote room
        const int g    = rem >> 3, l4 = rem & 7;
        const float* sp = zxp + (size_t)(b0 + g) * (R * L) + s * L + l4 * 4;
        float4 v;
        for (;;) {
            v.x = __hip_atomic_load(sp + 0, __ATOMIC_RELAXED, __HIP_MEMORY_SCOPE_AGENT);
            v.y = __hip_atomic_load(sp + 1, __ATOMIC_RELAXED, __HIP_MEMORY_SCOPE_AGENT);
            v.z = __hip_atomic_load(sp + 2, __ATOMIC_RELAXED, __HIP_MEMORY_SCOPE_AGENT);
            v.w = __hip_atomic_load(sp + 3, __ATOMIC_RELAXED, __HIP_MEMORY_SCOPE_AGENT);
            if (v.x == v.x && v.y == v.y && v.z == v.z && v.w == v.w) break;
            __builtin_amdgcn_s_sleep(1);
        }
        ((float4*)zS)[g * (R * L / 4) + s * (L / 4) + l4] = v;
    };

    for (int t = 0; t < T; ++t) {
        // ---- P1: mean (W0-2: 0-175) | gh (W3-4: 192-287) ----
        if (tid < 176) {
            const int sr = edgeSrc[tid >> 4];
#pragma unroll
            for (int g = 0; g < G; ++g) {
                const float4* zp = (const float4*)(zS + g * (R * L) + sr * L);
                float a = biasA;
#pragma unroll
                for (int c = 0; c < 8; ++c) a = fma4(wbuf[c], zp[c], a);
                meanS[g * 176 + tid] = a;
            }
        } else if (tid >= 192 && tid < 288) {
            const int j = tid - 192;
#pragma unroll
            for (int g = 0; g < G; ++g) {
                const float4* hp = (const float4*)(hSS + g * HH);
                float a = biasA;
#pragma unroll
                for (int c = 0; c < 8; ++c) a = fma4(wbuf[c], hp[c], a);
                ghSS[g * G3 + j] = a;
            }
        }
        sync_lds();

        // ---- P2: inc (W0-1: 0-127, wadd in regs) | poison (W7 upper) ----
        if (tid < 128) {
            const int g = tid >> 5;
            const float4* mp = (const float4*)(meanS + g * 176);
            float a = 0.f;
#pragma unroll
            for (int e = 0; e < 11; ++e)
#pragma unroll
                for (int c = 0; c < 4; ++c)
                    a = fma4(wbuf[8 + e * 4 + c], mp[e * 4 + c], a);
            incS[tid] = a;      // tid = g*32+l
        } else if (tid >= 480 && t >= 1) {
            // Poison own room's record in the buffer last read 2 steps ago.
            // Ordering vs this step's publish is intra-wave-7 (drain in P3).
            float* __restrict__ zq = zx + (size_t)((t - 1) % 3) * ZXN;
            const int i = tid - 480;              // 0..31
            const int g = i >> 3, l4 = i & 7;
            float* pp = zq + (size_t)(b0 + g) * (R * L) + r * L + l4 * 4;
#pragma unroll
            for (int w = 0; w < 4; ++w)
                __hip_atomic_store(pp + w, NANF, __ATOMIC_RELAXED,
                                   __HIP_MEMORY_SCOPE_AGENT);
        }
        sync_lds();

        // ---- P3: gate (W3: 192-223) | silu (W4: 256-319) | gi (W5-6: 320-415)
        //         | W7: private poison drain ----
        if (tid >= 192 && tid < 224) {
            const int j = tid - 192;
#pragma unroll
            for (int g = 0; g < G; ++g) {
                const float4* zp = (const float4*)(zS + g * (R * L) + r * L);
                const float4* ip = (const float4*)(incS + g * L);
                float a = biasB;
#pragma unroll
                for (int c = 0; c < 8; ++c) {
                    a = fma4(wbuf[8 + c], zp[c], a);
                    a = fma4(wbuf[16 + c], ip[c], a);
                }
                gateS[g * L + j] = sigmoidf(a);
            }
        } else if (tid >= 256 && tid < 320) {
            const int j = tid - 256;
#pragma unroll
            for (int g = 0; g < G; ++g) {
                const float4* zp = (const float4*)(zS + g * (R * L) + r * L);
                const float4* ip = (const float4*)(incS + g * L);
                float a = biasB;
#pragma unroll
                for (int c = 0; c < 8; ++c) {
                    a = fma4(wbuf[8 + c], zp[c], a);
                    a = fma4(wbuf[16 + c], ip[c], a);
                }
                shSS[g * HF + j] = a * sigmoidf(a);
            }
        } else if (tid >= 320 && tid < 416) {
            const int j = tid - 320;
#pragma unroll
            for (int g = 0; g < G; ++g) {
                const float4* ip = (const float4*)(incS + g * L);
                float a = biasA;
#pragma unroll
                for (int c = 0; c < 8; ++c) a = fma4(wbuf[c], ip[c], a);
                giSS[g * G3 + j] = a;
            }
        } else if (tid >= 448) {
            // Wave 7 (s_waitcnt is wave-scalar): drain poison stores while
            // other waves compute P3; publish (same wave) issues after.
            asm volatile("s_waitcnt vmcnt(0)" ::: "memory");
        }
        sync_lds();

        // ---- P4: zout+publish (W7: 448-479) | GRU+fetch (W5-6: 320-447)
        //         | msgs+fetch (W0-2: 0-191) | fetch (W3-4: 192-319) ----
        float* __restrict__ zxp = zx + (size_t)((t + 1) % 3) * ZXN;
        if (tid >= 448 && tid < 480) {
            const int j = tid - 448;
#pragma unroll
            for (int g = 0; g < G; ++g) {
                const float4* sp = (const float4*)(shSS + g * HF);
                float a = biasB;
#pragma unroll
                for (int c = 0; c < 16; ++c) a = fma4(wbuf[8 + c], sp[c], a);
                const float target = tanhf(a);
                const float zv = zS[g * (R * L) + r * L + j];
                const float znew = zv + DT * gateS[g * L + j] * (target - zv);
                zS[g * (R * L) + r * L + j] = znew;   // own-room z stays in LDS
                if (t + 1 < T)
                    __hip_atomic_store(&zxp[(size_t)(b0 + g) * (R * L) + r * L + j],
                                       znew, __ATOMIC_RELAXED,
                                       __HIP_MEMORY_SCOPE_AGENT);
                __builtin_nontemporal_store(
                    znew, &out_z[((size_t)(b0 + g) * T + t) * (R * L) + r * L + j]);
            }
        } else if (tid >= 320 && tid < 448) {
            const int i = tid - 320;
            const int g = i >> 5, hh = i & 31;
            const float ir  = giSS[g * G3 + hh];
            const float iz  = giSS[g * G3 + HH + hh];
            const float inn = giSS[g * G3 + 2 * HH + hh];
            const float hr  = ghSS[g * G3 + hh];
            const float hz  = ghSS[g * G3 + HH + hh];
            const float hnv = ghSS[g * G3 + 2 * HH + hh];
            const float reset = sigmoidf(ir + hr);
            const float upd   = sigmoidf(iz + hz);
            const float nw    = tanhf(inn + reset * hnv);
            hSS[g * HH + hh] = (1.0f - upd) * nw + upd * hSS[g * HH + hh];
            if (t + 1 < T) fetch_chunk(128 + i, zxp);          // chunks 128..255
        } else if (tid < 192) {
            if (tid < 176) {
                const int g = tid / 44, i = tid - g * 44;   // i in 0..43 (f4 over 11*M)
                const int el = i >> 2, m4 = i & 3;
                const f4v v = *(const f4v*)(meanS + g * 176 + i * 4);
                __builtin_nontemporal_store(
                    v, (f4v*)&out_msgs[((size_t)(b0 + g) * T + t) * (E * M)
                                       + edgeE[el] * 16 + m4 * 4]);
            }
            if (t + 1 < T && tid < 96) fetch_chunk(256 + tid, zxp); // 256..351
        } else if (tid >= 192 && tid < 320) {
            if (t + 1 < T) fetch_chunk(tid - 192, zxp);            // 0..127
        }
        sync_lds();
    }

    // ---- final h ----
    for (int i = tid; i < G * HH; i += BS) {
        const int g = i >> 5, hh = i & 31;
        __builtin_nontemporal_store(
            hSS[i], &out_hf[(size_t)(b0 + g) * R * HH + r * HH + hh]);
    }
}

extern "C" void kernel_launch(void* const* d_in, const int* in_sizes, int n_in,
                              void* d_out, int out_size, void* d_ws, size_t ws_size,
                              hipStream_t stream) {
    const float* z0     = (const float*)d_in[0];
    const float* h0     = (const float*)d_in[1];
    const float* mean_w = (const float*)d_in[2];
    const float* mean_b = (const float*)d_in[3];
    const float* add_w  = (const float*)d_in[4];
    const float* gsw    = (const float*)d_in[5];
    const float* gsb    = (const float*)d_in[6];
    const float* gcw    = (const float*)d_in[7];
    const float* lw     = (const float*)d_in[8];
    const float* lb     = (const float*)d_in[9];
    const float* ow_w   = (const float*)d_in[10];
    const float* ob     = (const float*)d_in[11];
    const float* wih    = (const float*)d_in[12];
    const float* whh    = (const float*)d_in[13];
    const float* bih    = (const float*)d_in[14];
    const float* bhh    = (const float*)d_in[15];
    const int* src_idx  = (const int*)d_in[16];
    const int* tgt_idx  = (const int*)d_in[17];
    const int* n_steps  = (const int*)d_in[18];

    const int B  = in_sizes[0] / (R * L);
    const int NG = B / G;   // batch groups

    float* zx = (float*)d_ws;    // 3 rotating buffers of B*R*L floats

    // Pre-poison all three buffers: every word = 0xFFFFFFFF = NaN sentinel.
    (void)hipMemsetAsync(zx, 0xFF, (size_t)3 * B * R * L * sizeof(float), stream);

    // 72000 B dynamic LDS: total 86.8KB/block > 80KB => hardware can place at
    // most ONE block per CU (160KB pool) => no persistent CU-sharing stragglers.
    nv_main<<<dim3(R, NG), dim3(BS), 72000, stream>>>(
        z0, h0, mean_w, mean_b, add_w, gsw, gsb, gcw, lw, lb, ow_w, ob,
        wih, whh, bih, bhh, src_idx, tgt_idx, n_steps,
        zx, (float*)d_out, B);
}

// Round 9
// 1047.841 us; speedup vs baseline: 1.8595x; 1.5973x over previous
//
#include <hip/hip_runtime.h>

// NeuroVoltron v13: v12's protocol + full wave-balancing + fitting registers.
//  - Root causes from v12 counters: VGPR_Count=128 => wbuf[52] still spilled
//    (scratch reads every step, FETCH_SIZE up); phases run on 1-3 of 8 waves
//    (latency-exposed ds_read->fma chains, idle LDS pipe).
//  - Per-thread weights capped at 24 f4 via role-slotted wbuf[32]:
//      [0..7]: meanW (0-175) | ghW (192-287)
//      [8..23]: siluW (0-255) | gateW gsw+gcw (256-383) | owW (384-511)
//    wadd -> LDS (v10 layout); wih -> LDS (gi carries no weights).
//  - Task spreading: P1 mean 0-175(x4)+gh 192-287(x4)+poison W7.
//    P2 inc 0-127 + msgs 128-303 + W7 vmcnt drain. P3 silu 0-255(x1) +
//    gate 256-383(x1) + gi 128-511(x1, wih from LDS). P4 zout 384-511(x1,
//    publish) + GRU 256-383 + fetch 0-351 (1 chunk each; W6-7 never spin).
//  - Exchange identical to v9-v12: NaN-sentinel data-poll, 3 rotating buffers,
//    lgkm-only barriers, poison buf(t-1)%3 (now P1, W7), W7 drains in P2.
// All dot-product summation orders unchanged => absmax 0.015625.

constexpr int R  = 12;
constexpr int L  = 32;
constexpr int M  = 16;
constexpr int HH = 32;
constexpr int HF = 64;
constexpr int E  = 132;
constexpr int G3 = 96;      // 3*HH
constexpr float DT = 0.1f;

constexpr int G  = 4;       // batch elements per block
constexpr int BS = 512;

typedef float f4v __attribute__((ext_vector_type(4)));   // nt-store-compatible

__device__ __forceinline__ float sigmoidf(float x) {
    return 1.0f / (1.0f + __expf(-x));
}
__device__ __forceinline__ float fma4(float4 a, float4 x, float acc) {
    acc = fmaf(a.x, x.x, acc);
    acc = fmaf(a.y, x.y, acc);
    acc = fmaf(a.z, x.z, acc);
    return fmaf(a.w, x.w, acc);
}

// Raw block barrier: LDS-only ordering (lgkmcnt), no vmcnt drain.
__device__ __forceinline__ void sync_lds() {
    asm volatile("s_waitcnt lgkmcnt(0)" ::: "memory");
    __builtin_amdgcn_s_barrier();
    asm volatile("" ::: "memory");
}

__global__ __launch_bounds__(BS)
__attribute__((amdgpu_waves_per_eu(2, 2)))
void nv_main(
    const float* __restrict__ z0,     const float* __restrict__ h0,
    const float* __restrict__ mean_w, const float* __restrict__ mean_b,
    const float* __restrict__ add_w,
    const float* __restrict__ gsw,    const float* __restrict__ gsb,
    const float* __restrict__ gcw,
    const float* __restrict__ lw,     const float* __restrict__ lb,
    const float* __restrict__ ow_w,   const float* __restrict__ ob,
    const float* __restrict__ wih,    const float* __restrict__ whh,
    const float* __restrict__ bih,    const float* __restrict__ bhh,
    const int* __restrict__ src_idx,  const int* __restrict__ tgt_idx,
    const int* __restrict__ n_steps_p,
    float* __restrict__ zx,
    float* __restrict__ out, int B)
{
    const int r   = blockIdx.x;       // room
    const int grp = blockIdx.y;       // batch group
    const int tid = threadIdx.x;
    const int T   = n_steps_p[0];
    const int b0  = grp * G;
    const size_t ZXN = (size_t)B * (R * L);   // one buffer's floats

    // output layout: z_traj (B,T,R,L) | h_f (B,R,HH) | msgs (B,T,E,M)
    float* __restrict__ out_z    = out;
    float* __restrict__ out_hf   = out + (size_t)B * T * R * L;
    float* __restrict__ out_msgs = out_hf + (size_t)B * R * HH;

    __shared__ __align__(16) float wadd_s[11 * L * M];   // [(e*4+c)*32+l] f4 over m
    __shared__ __align__(16) float wih_s[G3 * L];        // [j*32+k]
    __shared__ __align__(16) float zS[G * R * L];        // [g][room][l]
    __shared__ __align__(16) float hSS[G * HH];
    __shared__ __align__(16) float meanS[G * 11 * M];    // [g][e_local*16+m]
    __shared__ __align__(16) float incS[G * L];
    __shared__ __align__(16) float gateS[G * L];
    __shared__ __align__(16) float shSS[G * HF];
    __shared__ __align__(16) float giSS[G * G3];
    __shared__ __align__(16) float ghSS[G * G3];
    __shared__ int edgeE[11], edgeSrc[11];

    // ---- edge tables for this room ----
    if (tid == 0) {
        int c = 0;
        for (int e = 0; e < E; ++e)
            if (tgt_idx[e] == r) { edgeE[c] = e; edgeSrc[c] = src_idx[e]; ++c; }
    }
    __syncthreads();

    // ---- one-time: weights into role-slotted wbuf[32] (max 24 f4 used) ----
    float4 wbuf[32];
    float biasA = 0.f, biasB = 0.f, biasC = 0.f;

    if (tid < 176) {                       // meanW -> [0..7]
        const int el = tid >> 4, m = tid & 15;
        const int row = edgeE[el] * M + m;
        const float4* p = (const float4*)(mean_w + (size_t)row * L);
#pragma unroll
        for (int k = 0; k < 8; ++k) wbuf[k] = p[k];
        biasA = mean_b[row];
    }
    if (tid >= 192 && tid < 288) {         // ghW -> [0..7]
        const int j = tid - 192, row = r * G3 + j;
        const float4* p = (const float4*)(whh + (size_t)row * HH);
#pragma unroll
        for (int k = 0; k < 8; ++k) wbuf[k] = p[k];
        biasA = bhh[row];
    }
    if (tid < 256) {                       // siluW -> [8..23]
        const int j = tid & 63, row = r * HF + j;
        const float4* p = (const float4*)(lw + (size_t)row * 2 * L);
#pragma unroll
        for (int k = 0; k < 16; ++k) wbuf[8 + k] = p[k];
        biasB = lb[row];
    }
    if (tid >= 256 && tid < 384) {         // gateW: gsw->[8..15], gcw->[16..23]
        const int j = (tid - 256) & 31, row = r * L + j;
        const float4* pa = (const float4*)(gsw + (size_t)row * L);
        const float4* pb = (const float4*)(gcw + (size_t)row * L);
#pragma unroll
        for (int k = 0; k < 8; ++k) { wbuf[8 + k] = pa[k]; wbuf[16 + k] = pb[k]; }
        biasB = gsb[row];
    }
    if (tid >= 384) {                      // owW -> [8..23]
        const int j = (tid - 384) & 31, row = r * L + j;
        const float4* p = (const float4*)(ow_w + (size_t)row * HF);
#pragma unroll
        for (int k = 0; k < 16; ++k) wbuf[8 + k] = p[k];
        biasB = ob[row];
    }
    if (tid >= 128) {                      // gi bias (wih row from LDS)
        const int j = (tid - 128) % 96;
        biasC = bih[r * G3 + j];
    }

    // ---- one-time LDS weight staging ----
    for (int i = tid; i < 11 * L * M; i += BS) {      // wadd (v10 layout)
        const int e = i >> 9, rem = i & 511, l = rem >> 4, m = rem & 15;
        wadd_s[((e * 4 + (m >> 2)) * 32 + l) * 4 + (m & 3)] =
            add_w[((size_t)edgeE[e] * L + l) * M + m];
    }
    for (int i = tid; i < G3 * L; i += BS)            // wih rows
        wih_s[i] = wih[(size_t)r * G3 * L + i];

    // ---- state init ----
    for (int i = tid; i < G * R * L; i += BS) {
        const int g = i / (R * L), rl = i - g * (R * L);
        zS[i] = z0[(size_t)(b0 + g) * R * L + rl];
    }
    for (int i = tid; i < G * HH; i += BS) {
        const int g = i >> 5, hh = i & 31;
        hSS[i] = h0[(size_t)(b0 + g) * R * HH + r * HH + hh];
    }
    __syncthreads();

    const float NANF = __uint_as_float(0xFFFFFFFFu);

    for (int t = 0; t < T; ++t) {
        // ---- P1: mean (0-175, x4) | gh (192-287, x4) | poison (480-511) ----
        if (tid < 176) {
            const int sr = edgeSrc[tid >> 4];
#pragma unroll
            for (int g = 0; g < G; ++g) {
                const float4* zp = (const float4*)(zS + g * (R * L) + sr * L);
                float a = biasA;
#pragma unroll
                for (int c = 0; c < 8; ++c) a = fma4(wbuf[c], zp[c], a);
                meanS[g * 176 + tid] = a;
            }
        } else if (tid >= 192 && tid < 288) {
            const int j = tid - 192;
#pragma unroll
            for (int g = 0; g < G; ++g) {
                const float4* hp = (const float4*)(hSS + g * HH);
                float a = biasA;
#pragma unroll
                for (int c = 0; c < 8; ++c) a = fma4(wbuf[c], hp[c], a);
                ghSS[g * G3 + j] = a;
            }
        } else if (tid >= 480 && t >= 1) {
            // Poison own record in buf (t-1)%3 (read 2 steps ago). W7-only;
            // drained by W7's vmcnt(0) in P2, before any publish into that
            // buffer (next publish of it is step t+1 P4, after that barrier).
            float* __restrict__ zq = zx + (size_t)((t - 1) % 3) * ZXN;
            const int i = tid - 480;              // 0..31
            const int g = i >> 3, l4 = i & 7;
            float* pp = zq + (size_t)(b0 + g) * (R * L) + r * L + l4 * 4;
#pragma unroll
            for (int w = 0; w < 4; ++w)
                __hip_atomic_store(pp + w, NANF, __ATOMIC_RELAXED,
                                   __HIP_MEMORY_SCOPE_AGENT);
        }
        sync_lds();

        // ---- P2: inc (0-127) | msgs (128-303) | W7 drain (448+) ----
        if (tid < 128) {
            const int g = tid >> 5;
            const float4* mp = (const float4*)(meanS + g * 176);
            const float4* wp = (const float4*)wadd_s;
            const int l = tid & 31;
            float a = 0.f;
#pragma unroll
            for (int e = 0; e < 11; ++e)
#pragma unroll
                for (int c = 0; c < 4; ++c)
                    a = fma4(wp[(e * 4 + c) * 32 + l], mp[e * 4 + c], a);
            incS[tid] = a;      // tid = g*32+l
        } else if (tid < 304) {
            const int k = tid - 128;                       // 0..175
            const int g = k / 44, i = k - g * 44;          // i in 0..43
            const int el = i >> 2, m4 = i & 3;
            const f4v v = *(const f4v*)(meanS + g * 176 + i * 4);
            __builtin_nontemporal_store(
                v, (f4v*)&out_msgs[((size_t)(b0 + g) * T + t) * (E * M)
                                   + edgeE[el] * 16 + m4 * 4]);
        } else if (tid >= 448) {
            // Wave 7 (s_waitcnt is wave-scalar): ack the P1 poison stores
            // while other waves run P2; publishes happen after barriers.
            asm volatile("s_waitcnt vmcnt(0)" ::: "memory");
        }
        sync_lds();

        // ---- P3: silu (0-255,x1) | gate (256-383,x1) | gi (128-511,x1) ----
        if (tid < 256) {
            const int j = tid & 63, g = tid >> 6;
            const float4* zp = (const float4*)(zS + g * (R * L) + r * L);
            const float4* ip = (const float4*)(incS + g * L);
            float a = biasB;
#pragma unroll
            for (int c = 0; c < 8; ++c) {
                a = fma4(wbuf[8 + c], zp[c], a);
                a = fma4(wbuf[16 + c], ip[c], a);
            }
            shSS[g * HF + j] = a * sigmoidf(a);
        } else if (tid < 384) {
            const int k = tid - 256;
            const int j = k & 31, g = k >> 5;
            const float4* zp = (const float4*)(zS + g * (R * L) + r * L);
            const float4* ip = (const float4*)(incS + g * L);
            float a = biasB;
#pragma unroll
            for (int c = 0; c < 8; ++c) {
                a = fma4(wbuf[8 + c], zp[c], a);
                a = fma4(wbuf[16 + c], ip[c], a);
            }
            gateS[g * L + j] = sigmoidf(a);
        }
        if (tid >= 128) {                  // gi, wih row from LDS
            const int k = tid - 128;                       // 0..383
            const int j = k % 96, g = k / 96;
            const float4* wp = (const float4*)wih_s + j * 8;
            const float4* ip = (const float4*)(incS + g * L);
            float a = biasC;
#pragma unroll
            for (int c = 0; c < 8; ++c) a = fma4(wp[c], ip[c], a);
            giSS[g * G3 + j] = a;
        }
        sync_lds();

        // ---- P4: zout+publish (384-511,x1; W6-7) | GRU (256-383)
        //         | fetch (0-351, 1 chunk each; W0-5 only) ----
        float* __restrict__ zxp = zx + (size_t)((t + 1) % 3) * ZXN;
        if (tid >= 384) {
            const int k = tid - 384;
            const int j = k & 31, g = k >> 5;
            const float4* sp = (const float4*)(shSS + g * HF);
            float a = biasB;
#pragma unroll
            for (int c = 0; c < 16; ++c) a = fma4(wbuf[8 + c], sp[c], a);
            const float target = tanhf(a);
            const float zv = zS[g * (R * L) + r * L + j];
            const float znew = zv + DT * gateS[g * L + j] * (target - zv);
            zS[g * (R * L) + r * L + j] = znew;   // own-room z stays in LDS
            if (t + 1 < T)
                __hip_atomic_store(&zxp[(size_t)(b0 + g) * (R * L) + r * L + j],
                                   znew, __ATOMIC_RELAXED,
                                   __HIP_MEMORY_SCOPE_AGENT);
            __builtin_nontemporal_store(
                znew, &out_z[((size_t)(b0 + g) * T + t) * (R * L) + r * L + j]);
        } else {
            if (tid >= 256) {              // GRU (W4-5)
                const int i = tid - 256;
                const int g = i >> 5, hh = i & 31;
                const float ir  = giSS[g * G3 + hh];
                const float iz  = giSS[g * G3 + HH + hh];
                const float inn = giSS[g * G3 + 2 * HH + hh];
                const float hr  = ghSS[g * G3 + hh];
                const float hz  = ghSS[g * G3 + HH + hh];
                const float hnv = ghSS[g * G3 + 2 * HH + hh];
                const float reset = sigmoidf(ir + hr);
                const float upd   = sigmoidf(iz + hz);
                const float nw    = tanhf(inn + reset * hnv);
                hSS[g * HH + hh] = (1.0f - upd) * nw + upd * hSS[g * HH + hh];
            }
            if (tid < 352 && t + 1 < T) {  // fetch: chunk c = tid (0..351)
                const int team = tid >> 5, rem = tid & 31;
                const int s    = team + (team >= r ? 1 : 0);   // remote room
                const int g    = rem >> 3, l4 = rem & 7;
                const float* sp =
                    zxp + (size_t)(b0 + g) * (R * L) + s * L + l4 * 4;
                float4 v;
                for (;;) {
                    v.x = __hip_atomic_load(sp + 0, __ATOMIC_RELAXED, __HIP_MEMORY_SCOPE_AGENT);
                    v.y = __hip_atomic_load(sp + 1, __ATOMIC_RELAXED, __HIP_MEMORY_SCOPE_AGENT);
                    v.z = __hip_atomic_load(sp + 2, __ATOMIC_RELAXED, __HIP_MEMORY_SCOPE_AGENT);
                    v.w = __hip_atomic_load(sp + 3, __ATOMIC_RELAXED, __HIP_MEMORY_SCOPE_AGENT);
                    if (v.x == v.x && v.y == v.y && v.z == v.z && v.w == v.w)
                        break;
                    __builtin_amdgcn_s_sleep(1);
                }
                ((float4*)zS)[g * (R * L / 4) + s * (L / 4) + l4] = v;
            }
        }
        sync_lds();
    }

    // ---- final h ----
    for (int i = tid; i < G * HH; i += BS) {
        const int g = i >> 5, hh = i & 31;
        __builtin_nontemporal_store(
            hSS[i], &out_hf[(size_t)(b0 + g) * R * HH + r * HH + hh]);
    }
}

extern "C" void kernel_launch(void* const* d_in, const int* in_sizes, int n_in,
                              void* d_out, int out_size, void* d_ws, size_t ws_size,
                              hipStream_t stream) {
    const float* z0     = (const float*)d_in[0];
    const float* h0     = (const float*)d_in[1];
    const float* mean_w = (const float*)d_in[2];
    const float* mean_b = (const float*)d_in[3];
    const float* add_w  = (const float*)d_in[4];
    const float* gsw    = (const float*)d_in[5];
    const float* gsb    = (const float*)d_in[6];
    const float* gcw    = (const float*)d_in[7];
    const float* lw     = (const float*)d_in[8];
    const float* lb     = (const float*)d_in[9];
    const float* ow_w   = (const float*)d_in[10];
    const float* ob     = (const float*)d_in[11];
    const float* wih    = (const float*)d_in[12];
    const float* whh    = (const float*)d_in[13];
    const float* bih    = (const float*)d_in[14];
    const float* bhh    = (const float*)d_in[15];
    const int* src_idx  = (const int*)d_in[16];
    const int* tgt_idx  = (const int*)d_in[17];
    const int* n_steps  = (const int*)d_in[18];

    const int B  = in_sizes[0] / (R * L);
    const int NG = B / G;   // batch groups

    float* zx = (float*)d_ws;    // 3 rotating buffers of B*R*L floats

    // Pre-poison all three buffers: every word = 0xFFFFFFFF = NaN sentinel.
    (void)hipMemsetAsync(zx, 0xFF, (size_t)3 * B * R * L * sizeof(float), stream);

    // 72000 B dynamic LDS (+~49KB static = ~121KB) => at most one block per CU
    // => no persistent CU-sharing stragglers.
    nv_main<<<dim3(R, NG), dim3(BS), 72000, stream>>>(
        z0, h0, mean_w, mean_b, add_w, gsw, gsb, gcw, lw, lb, ow_w, ob,
        wih, whh, bih, bhh, src_idx, tgt_idx, n_steps,
        zx, (float*)d_out, B);
}

// Round 10
// 903.136 us; speedup vs baseline: 2.1575x; 1.1602x over previous
//
#include <hip/hip_runtime.h>

// NeuroVoltron v14: v13 + LDS bank-conflict elimination + P1/P2 rebalance.
//  - v13's counters: SQ_LDS_BANK_CONFLICT 1.0M -> 52.7M. Cause: wih_s rows at
//    stride 128B (all 64 lanes of gi hit bank-start 4c). Fix: XOR-swizzle
//    chunk slot = c ^ (j&7)  (T2 recipe). zS room stride 32->36 floats and
//    incS g-stride 32->36 kill the 4-way stride-128 aliasing in P1/P3.
//  - Rebalance: P1 mean on 352 thr x2 (was 176x4); gh into P2 slack (384-479);
//    poison P1 W7-upper; W7 vmcnt drain in P2 (same ordering proof as v13:
//    poison ack before any later publish into that buffer). Publishers (W6-7,
//    P4) never spin; spinners (fetch 0-351) never publish.
//  - Exchange identical to v9-v13: NaN-sentinel data-poll, 3 rotating buffers,
//    lgkm-only barriers, 72KB dynamic LDS => 1 block/CU.
// All dot-product summation orders unchanged => absmax 0.015625.

constexpr int R  = 12;
constexpr int L  = 32;
constexpr int M  = 16;
constexpr int HH = 32;
constexpr int HF = 64;
constexpr int E  = 132;
constexpr int G3 = 96;      // 3*HH
constexpr float DT = 0.1f;

constexpr int G  = 4;       // batch elements per block
constexpr int BS = 512;
constexpr int ZR = 36;      // zS room stride (floats), de-pow2
constexpr int ZG = R * ZR;  // 432
constexpr int IS = 36;      // incS g stride

typedef float f4v __attribute__((ext_vector_type(4)));   // nt-store-compatible

__device__ __forceinline__ float sigmoidf(float x) {
    return 1.0f / (1.0f + __expf(-x));
}
__device__ __forceinline__ float fma4(float4 a, float4 x, float acc) {
    acc = fmaf(a.x, x.x, acc);
    acc = fmaf(a.y, x.y, acc);
    acc = fmaf(a.z, x.z, acc);
    return fmaf(a.w, x.w, acc);
}

// Raw block barrier: LDS-only ordering (lgkmcnt), no vmcnt drain.
__device__ __forceinline__ void sync_lds() {
    asm volatile("s_waitcnt lgkmcnt(0)" ::: "memory");
    __builtin_amdgcn_s_barrier();
    asm volatile("" ::: "memory");
}

__global__ __launch_bounds__(BS)
__attribute__((amdgpu_waves_per_eu(2, 2)))
void nv_main(
    const float* __restrict__ z0,     const float* __restrict__ h0,
    const float* __restrict__ mean_w, const float* __restrict__ mean_b,
    const float* __restrict__ add_w,
    const float* __restrict__ gsw,    const float* __restrict__ gsb,
    const float* __restrict__ gcw,
    const float* __restrict__ lw,     const float* __restrict__ lb,
    const float* __restrict__ ow_w,   const float* __restrict__ ob,
    const float* __restrict__ wih,    const float* __restrict__ whh,
    const float* __restrict__ bih,    const float* __restrict__ bhh,
    const int* __restrict__ src_idx,  const int* __restrict__ tgt_idx,
    const int* __restrict__ n_steps_p,
    float* __restrict__ zx,
    float* __restrict__ out, int B)
{
    const int r   = blockIdx.x;       // room
    const int grp = blockIdx.y;       // batch group
    const int tid = threadIdx.x;
    const int T   = n_steps_p[0];
    const int b0  = grp * G;
    const size_t ZXN = (size_t)B * (R * L);   // one buffer's floats

    // output layout: z_traj (B,T,R,L) | h_f (B,R,HH) | msgs (B,T,E,M)
    float* __restrict__ out_z    = out;
    float* __restrict__ out_hf   = out + (size_t)B * T * R * L;
    float* __restrict__ out_msgs = out_hf + (size_t)B * R * HH;

    __shared__ __align__(16) float wadd_s[11 * L * M];   // [(e*4+c)*32+l] f4 over m
    __shared__ __align__(16) float wih_s[G3 * L];        // XOR-swizzled chunks
    __shared__ __align__(16) float zS[G * ZG];           // [g][room(ZR)][l]
    __shared__ __align__(16) float hSS[G * HH];
    __shared__ __align__(16) float meanS[G * 11 * M];    // [g][row]
    __shared__ __align__(16) float incS[G * IS];
    __shared__ __align__(16) float gateS[G * L];
    __shared__ __align__(16) float shSS[G * HF];
    __shared__ __align__(16) float giSS[G * G3];
    __shared__ __align__(16) float ghSS[G * G3];
    __shared__ int edgeE[11], edgeSrc[11];

    // ---- edge tables for this room ----
    if (tid == 0) {
        int c = 0;
        for (int e = 0; e < E; ++e)
            if (tgt_idx[e] == r) { edgeE[c] = e; edgeSrc[c] = src_idx[e]; ++c; }
    }
    __syncthreads();

    // ---- one-time: weights into role-slotted wbuf[32] (max 24 f4 used) ----
    // [0..7]:  meanW (0-351, row tid%176) | ghW (384-479)
    // [8..23]: siluW (0-255) | gateW gsw+gcw (256-383) | owW (384-511)
    float4 wbuf[32];
    float biasA = 0.f, biasB = 0.f, biasC = 0.f;

    if (tid < 352) {                       // meanW -> [0..7]
        const int rowl = tid % 176;
        const int el = rowl >> 4, m = rowl & 15;
        const int row = edgeE[el] * M + m;
        const float4* p = (const float4*)(mean_w + (size_t)row * L);
#pragma unroll
        for (int k = 0; k < 8; ++k) wbuf[k] = p[k];
        biasA = mean_b[row];
    }
    if (tid >= 384 && tid < 480) {         // ghW -> [0..7]
        const int j = tid - 384, row = r * G3 + j;
        const float4* p = (const float4*)(whh + (size_t)row * HH);
#pragma unroll
        for (int k = 0; k < 8; ++k) wbuf[k] = p[k];
        biasA = bhh[row];
    }
    if (tid < 256) {                       // siluW -> [8..23]
        const int j = tid & 63, row = r * HF + j;
        const float4* p = (const float4*)(lw + (size_t)row * 2 * L);
#pragma unroll
        for (int k = 0; k < 16; ++k) wbuf[8 + k] = p[k];
        biasB = lb[row];
    }
    if (tid >= 256 && tid < 384) {         // gateW: gsw->[8..15], gcw->[16..23]
        const int j = (tid - 256) & 31, row = r * L + j;
        const float4* pa = (const float4*)(gsw + (size_t)row * L);
        const float4* pb = (const float4*)(gcw + (size_t)row * L);
#pragma unroll
        for (int k = 0; k < 8; ++k) { wbuf[8 + k] = pa[k]; wbuf[16 + k] = pb[k]; }
        biasB = gsb[row];
    }
    if (tid >= 384) {                      // owW -> [8..23]
        const int j = (tid - 384) & 31, row = r * L + j;
        const float4* p = (const float4*)(ow_w + (size_t)row * HF);
#pragma unroll
        for (int k = 0; k < 16; ++k) wbuf[8 + k] = p[k];
        biasB = ob[row];
    }
    if (tid >= 128) {                      // gi bias (wih row from LDS)
        const int j = (tid - 128) % 96;
        biasC = bih[r * G3 + j];
    }

    // ---- one-time LDS weight staging ----
    for (int i = tid; i < 11 * L * M; i += BS) {      // wadd (v10 layout)
        const int e = i >> 9, rem = i & 511, l = rem >> 4, m = rem & 15;
        wadd_s[((e * 4 + (m >> 2)) * 32 + l) * 4 + (m & 3)] =
            add_w[((size_t)edgeE[e] * L + l) * M + m];
    }
    for (int i = tid; i < G3 * L; i += BS) {          // wih, XOR-swizzled
        const int j = i >> 5, cw = i & 31, c = cw >> 2, w = cw & 3;
        wih_s[j * 32 + ((c ^ (j & 7)) << 2) + w] = wih[(size_t)r * G3 * L + i];
    }

    // ---- state init ----
    for (int i = tid; i < G * R * L; i += BS) {
        const int g = i / (R * L), rl = i - g * (R * L);
        const int room = rl >> 5, l = rl & 31;
        zS[g * ZG + room * ZR + l] = z0[(size_t)(b0 + g) * R * L + rl];
    }
    for (int i = tid; i < G * HH; i += BS) {
        const int g = i >> 5, hh = i & 31;
        hSS[i] = h0[(size_t)(b0 + g) * R * HH + r * HH + hh];
    }
    __syncthreads();

    const float NANF = __uint_as_float(0xFFFFFFFFu);

    for (int t = 0; t < T; ++t) {
        // ---- P1: mean (0-351, x2 g) | poison (480-511, t>=1) ----
        if (tid < 352) {
            const int rowl = tid % 176;
            const int sr = edgeSrc[rowl >> 4];
            const int gb = (tid < 176) ? 0 : 2;
#pragma unroll
            for (int gg = 0; gg < 2; ++gg) {
                const int g = gb + gg;
                const float4* zp = (const float4*)(zS + g * ZG + sr * ZR);
                float a = biasA;
#pragma unroll
                for (int c = 0; c < 8; ++c) a = fma4(wbuf[c], zp[c], a);
                meanS[g * 176 + rowl] = a;
            }
        } else if (tid >= 480 && t >= 1) {
            // Poison own record in buf (t-1)%3 (safe: every block passed its
            // step t-2 reads of it — same causal proof as v13).
            float* __restrict__ zq = zx + (size_t)((t - 1) % 3) * ZXN;
            const int i = tid - 480;              // 0..31
            const int g = i >> 3, l4 = i & 7;
            float* pp = zq + (size_t)(b0 + g) * (R * L) + r * L + l4 * 4;
#pragma unroll
            for (int w = 0; w < 4; ++w)
                __hip_atomic_store(pp + w, NANF, __ATOMIC_RELAXED,
                                   __HIP_MEMORY_SCOPE_AGENT);
        }
        sync_lds();

        // ---- P2: inc (0-127) | msgs (128-303) | gh (384-479, x4)
        //         | W7 drain (480-511 branch; wave-scalar waitcnt) ----
        if (tid < 128) {
            const int g = tid >> 5, l = tid & 31;
            const float4* mp = (const float4*)(meanS + g * 176);
            const float4* wp = (const float4*)wadd_s;
            float a = 0.f;
#pragma unroll
            for (int e = 0; e < 11; ++e)
#pragma unroll
                for (int c = 0; c < 4; ++c)
                    a = fma4(wp[(e * 4 + c) * 32 + l], mp[e * 4 + c], a);
            incS[g * IS + l] = a;
        } else if (tid < 304) {
            const int k = tid - 128;                       // 0..175
            const int g = k / 44, i = k - g * 44;          // i in 0..43
            const int el = i >> 2, m4 = i & 3;
            const f4v v = *(const f4v*)(meanS + g * 176 + i * 4);
            __builtin_nontemporal_store(
                v, (f4v*)&out_msgs[((size_t)(b0 + g) * T + t) * (E * M)
                                   + edgeE[el] * 16 + m4 * 4]);
        } else if (tid >= 384 && tid < 480) {
            const int j = tid - 384;
#pragma unroll
            for (int g = 0; g < G; ++g) {
                const float4* hp = (const float4*)(hSS + g * HH);
                float a = biasA;
#pragma unroll
                for (int c = 0; c < 8; ++c) a = fma4(wbuf[c], hp[c], a);
                ghSS[g * G3 + j] = a;
            }
        } else if (tid >= 480) {
            // Wave 7: ack P1 poison stores before any later publish into that
            // buffer (publish into it is step t+1 P4, after many barriers).
            asm volatile("s_waitcnt vmcnt(0)" ::: "memory");
        }
        sync_lds();

        // ---- P3: silu (0-255,x1) | gate (256-383,x1) | gi (128-511,x1) ----
        if (tid < 256) {
            const int j = tid & 63, g = tid >> 6;
            const float4* zp = (const float4*)(zS + g * ZG + r * ZR);
            const float4* ip = (const float4*)(incS + g * IS);
            float a = biasB;
#pragma unroll
            for (int c = 0; c < 8; ++c) {
                a = fma4(wbuf[8 + c], zp[c], a);
                a = fma4(wbuf[16 + c], ip[c], a);
            }
            shSS[g * HF + j] = a * sigmoidf(a);
        } else if (tid < 384) {
            const int k = tid - 256;
            const int j = k & 31, g = k >> 5;
            const float4* zp = (const float4*)(zS + g * ZG + r * ZR);
            const float4* ip = (const float4*)(incS + g * IS);
            float a = biasB;
#pragma unroll
            for (int c = 0; c < 8; ++c) {
                a = fma4(wbuf[8 + c], zp[c], a);
                a = fma4(wbuf[16 + c], ip[c], a);
            }
            gateS[g * L + j] = sigmoidf(a);
        }
        if (tid >= 128) {                  // gi, swizzled wih_s
            const int k = tid - 128;                       // 0..383
            const int j = k % 96, g = k / 96;
            const float* wb = wih_s + j * 32;
            const int jx = j & 7;
            const float4* ip = (const float4*)(incS + g * IS);
            float a = biasC;
#pragma unroll
            for (int c = 0; c < 8; ++c)
                a = fma4(*(const float4*)(wb + ((c ^ jx) << 2)), ip[c], a);
            giSS[g * G3 + j] = a;
        }
        sync_lds();

        // ---- P4: zout+publish (384-511,x1; W6-7) | GRU (256-383)
        //         | fetch (0-351, 1 chunk each; W0-5 only) ----
        float* __restrict__ zxp = zx + (size_t)((t + 1) % 3) * ZXN;
        if (tid >= 384) {
            const int k = tid - 384;
            const int j = k & 31, g = k >> 5;
            const float4* sp = (const float4*)(shSS + g * HF);
            float a = biasB;
#pragma unroll
            for (int c = 0; c < 16; ++c) a = fma4(wbuf[8 + c], sp[c], a);
            const float target = tanhf(a);
            const float zv = zS[g * ZG + r * ZR + j];
            const float znew = zv + DT * gateS[g * L + j] * (target - zv);
            zS[g * ZG + r * ZR + j] = znew;   // own-room z stays in LDS
            if (t + 1 < T)
                __hip_atomic_store(&zxp[(size_t)(b0 + g) * (R * L) + r * L + j],
                                   znew, __ATOMIC_RELAXED,
                                   __HIP_MEMORY_SCOPE_AGENT);
            __builtin_nontemporal_store(
                znew, &out_z[((size_t)(b0 + g) * T + t) * (R * L) + r * L + j]);
        } else {
            if (tid >= 256) {              // GRU (W4-5)
                const int i = tid - 256;
                const int g = i >> 5, hh = i & 31;
                const float ir  = giSS[g * G3 + hh];
                const float iz  = giSS[g * G3 + HH + hh];
                const float inn = giSS[g * G3 + 2 * HH + hh];
                const float hr  = ghSS[g * G3 + hh];
                const float hz  = ghSS[g * G3 + HH + hh];
                const float hnv = ghSS[g * G3 + 2 * HH + hh];
                const float reset = sigmoidf(ir + hr);
                const float upd   = sigmoidf(iz + hz);
                const float nw    = tanhf(inn + reset * hnv);
                hSS[g * HH + hh] = (1.0f - upd) * nw + upd * hSS[g * HH + hh];
            }
            if (tid < 352 && t + 1 < T) {  // fetch: chunk c = tid (0..351)
                const int team = tid >> 5, rem = tid & 31;
                const int s    = team + (team >= r ? 1 : 0);   // remote room
                const int g    = rem >> 3, l4 = rem & 7;
                const float* sp =
                    zxp + (size_t)(b0 + g) * (R * L) + s * L + l4 * 4;
                float4 v;
                for (;;) {
                    v.x = __hip_atomic_load(sp + 0, __ATOMIC_RELAXED, __HIP_MEMORY_SCOPE_AGENT);
                    v.y = __hip_atomic_load(sp + 1, __ATOMIC_RELAXED, __HIP_MEMORY_SCOPE_AGENT);
                    v.z = __hip_atomic_load(sp + 2, __ATOMIC_RELAXED, __HIP_MEMORY_SCOPE_AGENT);
                    v.w = __hip_atomic_load(sp + 3, __ATOMIC_RELAXED, __HIP_MEMORY_SCOPE_AGENT);
                    if (v.x == v.x && v.y == v.y && v.z == v.z && v.w == v.w)
                        break;
                    __builtin_amdgcn_s_sleep(1);
                }
                *(float4*)(zS + g * ZG + s * ZR + l4 * 4) = v;
            }
        }
        sync_lds();
    }

    // ---- final h ----
    for (int i = tid; i < G * HH; i += BS) {
        const int g = i >> 5, hh = i & 31;
        __builtin_nontemporal_store(
            hSS[i], &out_hf[(size_t)(b0 + g) * R * HH + r * HH + hh]);
    }
}

extern "C" void kernel_launch(void* const* d_in, const int* in_sizes, int n_in,
                              void* d_out, int out_size, void* d_ws, size_t ws_size,
                              hipStream_t stream) {
    const float* z0     = (const float*)d_in[0];
    const float* h0     = (const float*)d_in[1];
    const float* mean_w = (const float*)d_in[2];
    const float* mean_b = (const float*)d_in[3];
    const float* add_w  = (const float*)d_in[4];
    const float* gsw    = (const float*)d_in[5];
    const float* gsb    = (const float*)d_in[6];
    const float* gcw    = (const float*)d_in[7];
    const float* lw     = (const float*)d_in[8];
    const float* lb     = (const float*)d_in[9];
    const float* ow_w   = (const float*)d_in[10];
    const float* ob     = (const float*)d_in[11];
    const float* wih    = (const float*)d_in[12];
    const float* whh    = (const float*)d_in[13];
    const float* bih    = (const float*)d_in[14];
    const float* bhh    = (const float*)d_in[15];
    const int* src_idx  = (const int*)d_in[16];
    const int* tgt_idx  = (const int*)d_in[17];
    const int* n_steps  = (const int*)d_in[18];

    const int B  = in_sizes[0] / (R * L);
    const int NG = B / G;   // batch groups

    float* zx = (float*)d_ws;    // 3 rotating buffers of B*R*L floats

    // Pre-poison all three buffers: every word = 0xFFFFFFFF = NaN sentinel.
    (void)hipMemsetAsync(zx, 0xFF, (size_t)3 * B * R * L * sizeof(float), stream);

    // 72000 B dynamic LDS (+~51KB static = ~123KB) => at most one block per CU
    // => no persistent CU-sharing stragglers.
    nv_main<<<dim3(R, NG), dim3(BS), 72000, stream>>>(
        z0, h0, mean_w, mean_b, add_w, gsw, gsb, gcw, lw, lb, ow_w, ob,
        wih, whh, bih, bhh, src_idx, tgt_idx, n_steps,
        zx, (float*)d_out, B);
}